// Round 1
// baseline (400.144 us; speedup 1.0000x reference)
//
#include <hip/hip_runtime.h>
#include <math.h>

// Problem constants
constexpr int CB = 32;      // batch
constexpr int CL = 256;     // seq len
constexpr int CD = 768;     // bert dim
constexpr int CATT = 100;   // att dim
constexpr int CH = 5;       // heads
constexpr int CDK = 20;     // head dim

__device__ __forceinline__ void fma4(float4& a, float s, const float4& w) {
    a.x = fmaf(s, w.x, a.x);
    a.y = fmaf(s, w.y, a.y);
    a.z = fmaf(s, w.z, a.z);
    a.w = fmaf(s, w.w, a.w);
}

// ---------------------------------------------------------------------------
// Kernel 1: fused layernorm (ddof=1, eps on std) + g = xn @ Wxx_w + Wxx_b
// grid 256 blocks (32 rows each), 256 threads
// ---------------------------------------------------------------------------
__global__ __launch_bounds__(256) void k1_ln_g(
    const float* __restrict__ x, const float* __restrict__ ln_a,
    const float* __restrict__ ln_b, const float* __restrict__ Wxx_w,
    const float* __restrict__ Wxx_b, float* __restrict__ g)
{
    __shared__ float s_mean[32];
    __shared__ float s_rinv[32];
    __shared__ float s_xn[32 * 68];   // K-tile 32 rows x 64, stride 68

    const int t = threadIdx.x;
    const int r0 = blockIdx.x * 32;
    const int wid = t >> 6, lane = t & 63;

    // ---- stats: wave wid handles rows wid*8 .. wid*8+7 (wave-local reduce)
    for (int rr = wid * 8; rr < wid * 8 + 8; ++rr) {
        const float* xr = x + (size_t)(r0 + rr) * CD;
        float xv[12];
        float s = 0.f;
#pragma unroll
        for (int m = 0; m < 12; ++m) { xv[m] = xr[lane + 64 * m]; s += xv[m]; }
#pragma unroll
        for (int o = 32; o; o >>= 1) s += __shfl_xor(s, o);
        float mean = s * (1.0f / 768.0f);
        float sq = 0.f;
#pragma unroll
        for (int m = 0; m < 12; ++m) { float d = xv[m] - mean; sq = fmaf(d, d, sq); }
#pragma unroll
        for (int o = 32; o; o >>= 1) sq += __shfl_xor(sq, o);
        if (lane == 0) {
            s_mean[rr] = mean;
            s_rinv[rr] = 1.0f / (sqrtf(sq * (1.0f / 767.0f)) + 1e-6f);
        }
    }
    __syncthreads();

    const int cg = t % 25, rs = t / 25;
    const int c = cg * 4;
    float4 acc[4];
#pragma unroll
    for (int q = 0; q < 4; ++q) acc[q] = make_float4(0.f, 0.f, 0.f, 0.f);

    for (int kt = 0; kt < 12; ++kt) {
        // stage normalized K-tile into LDS
#pragma unroll
        for (int m = 0; m < 8; ++m) {
            int idx = t + 256 * m;
            int row = idx >> 6, kk = idx & 63;
            int k = kt * 64 + kk;
            float v = x[(size_t)(r0 + row) * CD + k];
            s_xn[row * 68 + kk] = fmaf(ln_a[k], (v - s_mean[row]) * s_rinv[row], ln_b[k]);
        }
        __syncthreads();
        if (t < 200) {
#pragma unroll
            for (int kk = 0; kk < 64; kk += 4) {
                float4 a0 = *(const float4*)&s_xn[(rs * 4 + 0) * 68 + kk];
                float4 a1 = *(const float4*)&s_xn[(rs * 4 + 1) * 68 + kk];
                float4 a2 = *(const float4*)&s_xn[(rs * 4 + 2) * 68 + kk];
                float4 a3 = *(const float4*)&s_xn[(rs * 4 + 3) * 68 + kk];
                const float* wp = Wxx_w + (size_t)(kt * 64 + kk) * CATT + c;
                float4 w0 = *(const float4*)(wp);
                float4 w1 = *(const float4*)(wp + CATT);
                float4 w2 = *(const float4*)(wp + 2 * CATT);
                float4 w3 = *(const float4*)(wp + 3 * CATT);
                fma4(acc[0], a0.x, w0); fma4(acc[0], a0.y, w1); fma4(acc[0], a0.z, w2); fma4(acc[0], a0.w, w3);
                fma4(acc[1], a1.x, w0); fma4(acc[1], a1.y, w1); fma4(acc[1], a1.z, w2); fma4(acc[1], a1.w, w3);
                fma4(acc[2], a2.x, w0); fma4(acc[2], a2.y, w1); fma4(acc[2], a2.z, w2); fma4(acc[2], a2.w, w3);
                fma4(acc[3], a3.x, w0); fma4(acc[3], a3.y, w1); fma4(acc[3], a3.z, w2); fma4(acc[3], a3.w, w3);
            }
        }
        __syncthreads();
    }
    if (t < 200) {
        float4 bias = *(const float4*)&Wxx_b[c];
#pragma unroll
        for (int q = 0; q < 4; ++q) {
            float4 r;
            r.x = acc[q].x + bias.x; r.y = acc[q].y + bias.y;
            r.z = acc[q].z + bias.z; r.w = acc[q].w + bias.w;
            *(float4*)&g[(size_t)(r0 + rs * 4 + q) * CATT + c] = r;
        }
    }
}

// ---------------------------------------------------------------------------
// Kernel 2: aspect pooling + asp = aspect @ dense_w + dense_b; also asp_wn
// grid 32 blocks (one per b), 256 threads
// ---------------------------------------------------------------------------
__global__ __launch_bounds__(256) void k2_aspect(
    const float* __restrict__ g, const float* __restrict__ amask,
    const float* __restrict__ dense_w, const float* __restrict__ dense_b,
    float* __restrict__ asp, float* __restrict__ aspwn)
{
    __shared__ float s_m[256];
    __shared__ float s_asp[100];
    __shared__ float red[4];
    const int b = blockIdx.x, t = threadIdx.x;
    const int wid = t >> 6, lane = t & 63;
    float mv = amask[b * CL + t];
    s_m[t] = mv;
    float s = mv;
#pragma unroll
    for (int o = 32; o; o >>= 1) s += __shfl_xor(s, o);
    if (lane == 0) red[wid] = s;
    __syncthreads();
    float wn = red[0] + red[1] + red[2] + red[3];
    if (t == 0) aspwn[b] = wn;
    if (t < 100) {
        float acc = 0.f;
        for (int l = 0; l < CL; ++l) acc = fmaf(s_m[l], g[(size_t)(b * CL + l) * CATT + t], acc);
        s_asp[t] = acc / wn;
    }
    __syncthreads();
    if (t < 20) {
        float a = dense_b[t];
        for (int d = 0; d < CATT; ++d) a = fmaf(s_asp[d], dense_w[d * CDK + t], a);
        asp[b * CDK + t] = a;
    }
}

// ---------------------------------------------------------------------------
// Kernel 3: q = g@q_w+q_b, k = g@k_w+k_b, written in (B,H,L,DK) layout
// grid 256 blocks (32 rows each), 256 threads
// ---------------------------------------------------------------------------
__global__ __launch_bounds__(256) void k3_qk(
    const float* __restrict__ g, const float* __restrict__ q_w,
    const float* __restrict__ q_b, const float* __restrict__ k_w,
    const float* __restrict__ k_b, float* __restrict__ qt,
    float* __restrict__ ktb)
{
    __shared__ float s_g[32 * 100];
    const int t = threadIdx.x;
    const int r0 = blockIdx.x * 32;
    for (int idx = t; idx < 3200; idx += 256) s_g[idx] = g[(size_t)r0 * CATT + idx];
    __syncthreads();
    if (t >= 200) return;
    const int cg = t % 25, rs = t / 25;
    const int c = cg * 4;
    const int h = c / CDK, d = c % CDK;
    for (int pass = 0; pass < 2; ++pass) {
        const float* W = pass ? k_w : q_w;
        const float* bb = pass ? k_b : q_b;
        float* out = pass ? ktb : qt;
        float4 acc[4];
#pragma unroll
        for (int q = 0; q < 4; ++q) acc[q] = make_float4(0.f, 0.f, 0.f, 0.f);
#pragma unroll
        for (int k = 0; k < 100; k += 4) {
            float4 a0 = *(const float4*)&s_g[(rs * 4 + 0) * 100 + k];
            float4 a1 = *(const float4*)&s_g[(rs * 4 + 1) * 100 + k];
            float4 a2 = *(const float4*)&s_g[(rs * 4 + 2) * 100 + k];
            float4 a3 = *(const float4*)&s_g[(rs * 4 + 3) * 100 + k];
            const float* wp = W + (size_t)k * CATT + c;
            float4 w0 = *(const float4*)(wp);
            float4 w1 = *(const float4*)(wp + CATT);
            float4 w2 = *(const float4*)(wp + 2 * CATT);
            float4 w3 = *(const float4*)(wp + 3 * CATT);
            fma4(acc[0], a0.x, w0); fma4(acc[0], a0.y, w1); fma4(acc[0], a0.z, w2); fma4(acc[0], a0.w, w3);
            fma4(acc[1], a1.x, w0); fma4(acc[1], a1.y, w1); fma4(acc[1], a1.z, w2); fma4(acc[1], a1.w, w3);
            fma4(acc[2], a2.x, w0); fma4(acc[2], a2.y, w1); fma4(acc[2], a2.z, w2); fma4(acc[2], a2.w, w3);
            fma4(acc[3], a3.x, w0); fma4(acc[3], a3.y, w1); fma4(acc[3], a3.z, w2); fma4(acc[3], a3.w, w3);
        }
        float4 bias = *(const float4*)&bb[c];
#pragma unroll
        for (int q = 0; q < 4; ++q) {
            int row = r0 + rs * 4 + q;
            int bidx = row >> 8, l = row & 255;
            float4 r;
            r.x = acc[q].x + bias.x; r.y = acc[q].y + bias.y;
            r.z = acc[q].z + bias.z; r.w = acc[q].w + bias.w;
            *(float4*)&out[((size_t)(bidx * CH + h) * CL + l) * CDK + d] = r;
        }
    }
}

// ---------------------------------------------------------------------------
// Kernel 4: scores + softmax, accumulate adjS = sum_h adj, adjW = sum_h adj*WaS[h]
// grid 32*16 blocks (b, 16-row i-chunk), 256 threads (thread = j)
// ---------------------------------------------------------------------------
__global__ __launch_bounds__(256) void k4_attn(
    const float* __restrict__ qt, const float* __restrict__ ktb,
    const float* __restrict__ asp, const float* __restrict__ bias_m,
    const int* __restrict__ src_mask, const float* __restrict__ shortm,
    const float* __restrict__ Wx_w, float* __restrict__ adjS,
    float* __restrict__ adjW)
{
    constexpr int ICH = 16;
    __shared__ float red[8];
    __shared__ float s_was[5];
    __shared__ float s_aspb[20];
    const int nch = CL / ICH;
    const int b = blockIdx.x / nch, ic = blockIdx.x % nch;
    const int t = threadIdx.x, lane = t & 63, wid = t >> 6;
    const int j = t;

    if (t < 5) {
        float s = 0.f;
        for (int k2 = 0; k2 < 5; ++k2) s += Wx_w[t * 5 + k2];
        s_was[t] = s;
    }
    if (t < 20) s_aspb[t] = asp[b * CDK + t];
    __syncthreads();

    const bool masked = (src_mask[b * CL + j] == 0);
    const float bm = bias_m[0];
    const float rs20 = 0.223606797749978969f;  // 1/sqrt(20)
    float accS[ICH], accW[ICH];
#pragma unroll
    for (int ii = 0; ii < ICH; ++ii) { accS[ii] = 0.f; accW[ii] = 0.f; }

    for (int h = 0; h < CH; ++h) {
        // k row for this j into registers
        float4 kr[5];
        const float* kp = ktb + ((size_t)(b * CH + h) * CL + j) * CDK;
#pragma unroll
        for (int m = 0; m < 5; ++m) kr[m] = *(const float4*)(kp + 4 * m);
        const float was_h = s_was[h];
        // asp_sc_j for this head
        float s = bm;
#pragma unroll
        for (int m = 0; m < 5; ++m) {
            s = fmaf(s_aspb[4 * m + 0], kr[m].x, s);
            s = fmaf(s_aspb[4 * m + 1], kr[m].y, s);
            s = fmaf(s_aspb[4 * m + 2], kr[m].z, s);
            s = fmaf(s_aspb[4 * m + 3], kr[m].w, s);
        }
        const float aspsc = tanhf(s);

        for (int ii = 0; ii < ICH; ++ii) {
            const int i = ic * ICH + ii;
            const float* qp = qt + ((size_t)(b * CH + h) * CL + i) * CDK;
            float sc = 0.f;
#pragma unroll
            for (int m = 0; m < 5; ++m) {
                float4 q4 = *(const float4*)(qp + 4 * m);
                sc = fmaf(q4.x, kr[m].x, sc);
                sc = fmaf(q4.y, kr[m].y, sc);
                sc = fmaf(q4.z, kr[m].z, sc);
                sc = fmaf(q4.w, kr[m].w, sc);
            }
            sc = fmaf(sc, rs20, aspsc) + shortm[(size_t)(b * CL + i) * CL + j];
            float p = masked ? 0.f : expf(sc);
            float ssum = p;
#pragma unroll
            for (int o = 32; o; o >>= 1) ssum += __shfl_xor(ssum, o);
            const int set = (ii & 1) * 4;
            if (lane == 0) red[set + wid] = ssum;
            __syncthreads();
            float tot = red[set] + red[set + 1] + red[set + 2] + red[set + 3];
            float pn = p * __frcp_rn(tot);
            accS[ii] += pn;
            accW[ii] = fmaf(was_h, pn, accW[ii]);
        }
    }
#pragma unroll
    for (int ii = 0; ii < ICH; ++ii) {
        const int i = ic * ICH + ii;
        adjS[(size_t)(b * CL + i) * CL + j] = accS[ii];
        adjW[(size_t)(b * CL + i) * CL + j] = accW[ii];
    }
}

// ---------------------------------------------------------------------------
// Kernel 5: GCN layer 0: Ax = adjS @ g / H ; go1 = relu(Ax @ W_w + W_b)
// grid 32*8 blocks (b, 32-row i-chunk), 256 threads
// ---------------------------------------------------------------------------
__global__ __launch_bounds__(256) void k5_gcn0(
    const float* __restrict__ adjS, const float* __restrict__ g,
    const float* __restrict__ W_w, const float* __restrict__ W_b,
    float* __restrict__ go1)
{
    __shared__ float s_adj[32 * 260];
    __shared__ float s_ax[32 * 108];
    const int t = threadIdx.x;
    const int b = blockIdx.x >> 3, ic = blockIdx.x & 7;
    const int i0 = ic * 32;
    for (int idx = t; idx < 32 * 256; idx += 256) {
        int row = idx >> 8, jj = idx & 255;
        s_adj[row * 260 + jj] = adjS[(size_t)(b * CL + i0 + row) * CL + jj];
    }
    __syncthreads();
    const int cg = t % 25, rs = t / 25;
    const int c = cg * 4;
    if (t < 200) {
        float4 acc[4];
#pragma unroll
        for (int q = 0; q < 4; ++q) acc[q] = make_float4(0.f, 0.f, 0.f, 0.f);
        for (int jj = 0; jj < 256; jj += 4) {
            float4 a0 = *(const float4*)&s_adj[(rs * 4 + 0) * 260 + jj];
            float4 a1 = *(const float4*)&s_adj[(rs * 4 + 1) * 260 + jj];
            float4 a2 = *(const float4*)&s_adj[(rs * 4 + 2) * 260 + jj];
            float4 a3 = *(const float4*)&s_adj[(rs * 4 + 3) * 260 + jj];
            const float* gp = g + (size_t)(b * CL + jj) * CATT + c;
            float4 g0 = *(const float4*)(gp);
            float4 g1 = *(const float4*)(gp + CATT);
            float4 g2 = *(const float4*)(gp + 2 * CATT);
            float4 g3 = *(const float4*)(gp + 3 * CATT);
            fma4(acc[0], a0.x, g0); fma4(acc[0], a0.y, g1); fma4(acc[0], a0.z, g2); fma4(acc[0], a0.w, g3);
            fma4(acc[1], a1.x, g0); fma4(acc[1], a1.y, g1); fma4(acc[1], a1.z, g2); fma4(acc[1], a1.w, g3);
            fma4(acc[2], a2.x, g0); fma4(acc[2], a2.y, g1); fma4(acc[2], a2.z, g2); fma4(acc[2], a2.w, g3);
            fma4(acc[3], a3.x, g0); fma4(acc[3], a3.y, g1); fma4(acc[3], a3.z, g2); fma4(acc[3], a3.w, g3);
        }
#pragma unroll
        for (int q = 0; q < 4; ++q) {
            float4 r;
            r.x = acc[q].x * 0.2f; r.y = acc[q].y * 0.2f;
            r.z = acc[q].z * 0.2f; r.w = acc[q].w * 0.2f;
            *(float4*)&s_ax[(rs * 4 + q) * 108 + c] = r;
        }
    }
    __syncthreads();
    if (t < 200) {
        float4 acc[4];
#pragma unroll
        for (int q = 0; q < 4; ++q) acc[q] = make_float4(0.f, 0.f, 0.f, 0.f);
#pragma unroll
        for (int dd = 0; dd < 100; dd += 4) {
            float4 a0 = *(const float4*)&s_ax[(rs * 4 + 0) * 108 + dd];
            float4 a1 = *(const float4*)&s_ax[(rs * 4 + 1) * 108 + dd];
            float4 a2 = *(const float4*)&s_ax[(rs * 4 + 2) * 108 + dd];
            float4 a3 = *(const float4*)&s_ax[(rs * 4 + 3) * 108 + dd];
            const float* wp = W_w + (size_t)dd * CATT + c;
            float4 w0 = *(const float4*)(wp);
            float4 w1 = *(const float4*)(wp + CATT);
            float4 w2 = *(const float4*)(wp + 2 * CATT);
            float4 w3 = *(const float4*)(wp + 3 * CATT);
            fma4(acc[0], a0.x, w0); fma4(acc[0], a0.y, w1); fma4(acc[0], a0.z, w2); fma4(acc[0], a0.w, w3);
            fma4(acc[1], a1.x, w0); fma4(acc[1], a1.y, w1); fma4(acc[1], a1.z, w2); fma4(acc[1], a1.w, w3);
            fma4(acc[2], a2.x, w0); fma4(acc[2], a2.y, w1); fma4(acc[2], a2.z, w2); fma4(acc[2], a2.w, w3);
            fma4(acc[3], a3.x, w0); fma4(acc[3], a3.y, w1); fma4(acc[3], a3.z, w2); fma4(acc[3], a3.w, w3);
        }
        float4 bias = *(const float4*)&W_b[c];
#pragma unroll
        for (int q = 0; q < 4; ++q) {
            float4 r;
            r.x = fmaxf(acc[q].x + bias.x, 0.f); r.y = fmaxf(acc[q].y + bias.y, 0.f);
            r.z = fmaxf(acc[q].z + bias.z, 0.f); r.w = fmaxf(acc[q].w + bias.w, 0.f);
            *(float4*)&go1[(size_t)(b * CL + i0 + rs * 4 + q) * CATT + c] = r;
        }
    }
}

// ---------------------------------------------------------------------------
// Kernel 6: per-b rank-1 pieces: gW2S[b,i], t1[b,d], t2[b,d]
// grid 32 blocks, 256 threads
// ---------------------------------------------------------------------------
__global__ __launch_bounds__(256) void k6_mid(
    const float* __restrict__ go1, const float* __restrict__ Wx_w,
    float* __restrict__ t1, float* __restrict__ t2, float* __restrict__ gW2S)
{
    __shared__ float s_w1[100];
    __shared__ float s_w2[100];
    __shared__ float s_g1[256];
    const int b = blockIdx.x, t = threadIdx.x;
    if (t < 100) {
        float a = 0.f, c2 = 0.f;
#pragma unroll
        for (int h = 0; h < 5; ++h) {
            a += Wx_w[(5 + t) * 5 + h];
            c2 += Wx_w[(105 + t) * 5 + h];
        }
        s_w1[t] = a; s_w2[t] = c2;
    }
    __syncthreads();
    {
        const float* gp = go1 + (size_t)(b * CL + t) * CATT;
        float a = 0.f, c2 = 0.f;
        for (int e = 0; e < 100; ++e) {
            float v = gp[e];
            a = fmaf(v, s_w1[e], a);
            c2 = fmaf(v, s_w2[e], c2);
        }
        s_g1[t] = a;
        gW2S[b * CL + t] = c2;
    }
    __syncthreads();
    if (t < 100) {
        float a = 0.f, s2 = 0.f;
        for (int jj = 0; jj < 256; ++jj) {
            float v = go1[(size_t)(b * CL + jj) * CATT + t];
            a = fmaf(s_g1[jj], v, a);
            s2 += v;
        }
        t1[b * CATT + t] = a;
        t2[b * CATT + t] = s2;
    }
}

// ---------------------------------------------------------------------------
// Kernel 7: GCN layer 1: Ax2 = (adjW@go1 + t1 + (gW2S[i]+WxbS)*t2)/H;
//           go2 = relu(Ax2 @ W_w + W_b)
// ---------------------------------------------------------------------------
__global__ __launch_bounds__(256) void k7_gcn1(
    const float* __restrict__ adjW, const float* __restrict__ go1,
    const float* __restrict__ W_w, const float* __restrict__ W_b,
    const float* __restrict__ t1, const float* __restrict__ t2,
    const float* __restrict__ gW2S, const float* __restrict__ Wx_b,
    float* __restrict__ go2)
{
    __shared__ float s_adj[32 * 260];
    __shared__ float s_ax[32 * 108];
    const int t = threadIdx.x;
    const int b = blockIdx.x >> 3, ic = blockIdx.x & 7;
    const int i0 = ic * 32;
    for (int idx = t; idx < 32 * 256; idx += 256) {
        int row = idx >> 8, jj = idx & 255;
        s_adj[row * 260 + jj] = adjW[(size_t)(b * CL + i0 + row) * CL + jj];
    }
    __syncthreads();
    const int cg = t % 25, rs = t / 25;
    const int c = cg * 4;
    if (t < 200) {
        float4 acc[4];
#pragma unroll
        for (int q = 0; q < 4; ++q) acc[q] = make_float4(0.f, 0.f, 0.f, 0.f);
        for (int jj = 0; jj < 256; jj += 4) {
            float4 a0 = *(const float4*)&s_adj[(rs * 4 + 0) * 260 + jj];
            float4 a1 = *(const float4*)&s_adj[(rs * 4 + 1) * 260 + jj];
            float4 a2 = *(const float4*)&s_adj[(rs * 4 + 2) * 260 + jj];
            float4 a3 = *(const float4*)&s_adj[(rs * 4 + 3) * 260 + jj];
            const float* gp = go1 + (size_t)(b * CL + jj) * CATT + c;
            float4 g0 = *(const float4*)(gp);
            float4 g1 = *(const float4*)(gp + CATT);
            float4 g2 = *(const float4*)(gp + 2 * CATT);
            float4 g3 = *(const float4*)(gp + 3 * CATT);
            fma4(acc[0], a0.x, g0); fma4(acc[0], a0.y, g1); fma4(acc[0], a0.z, g2); fma4(acc[0], a0.w, g3);
            fma4(acc[1], a1.x, g0); fma4(acc[1], a1.y, g1); fma4(acc[1], a1.z, g2); fma4(acc[1], a1.w, g3);
            fma4(acc[2], a2.x, g0); fma4(acc[2], a2.y, g1); fma4(acc[2], a2.z, g2); fma4(acc[2], a2.w, g3);
            fma4(acc[3], a3.x, g0); fma4(acc[3], a3.y, g1); fma4(acc[3], a3.z, g2); fma4(acc[3], a3.w, g3);
        }
        float wxbs = Wx_b[0] + Wx_b[1] + Wx_b[2] + Wx_b[3] + Wx_b[4];
        float4 t1v = *(const float4*)&t1[b * CATT + c];
        float4 t2v = *(const float4*)&t2[b * CATT + c];
#pragma unroll
        for (int q = 0; q < 4; ++q) {
            int i = i0 + rs * 4 + q;
            float gw2 = gW2S[b * CL + i] + wxbs;
            float4 r;
            r.x = (acc[q].x + t1v.x + gw2 * t2v.x) * 0.2f;
            r.y = (acc[q].y + t1v.y + gw2 * t2v.y) * 0.2f;
            r.z = (acc[q].z + t1v.z + gw2 * t2v.z) * 0.2f;
            r.w = (acc[q].w + t1v.w + gw2 * t2v.w) * 0.2f;
            *(float4*)&s_ax[(rs * 4 + q) * 108 + c] = r;
        }
    }
    __syncthreads();
    if (t < 200) {
        float4 acc[4];
#pragma unroll
        for (int q = 0; q < 4; ++q) acc[q] = make_float4(0.f, 0.f, 0.f, 0.f);
#pragma unroll
        for (int dd = 0; dd < 100; dd += 4) {
            float4 a0 = *(const float4*)&s_ax[(rs * 4 + 0) * 108 + dd];
            float4 a1 = *(const float4*)&s_ax[(rs * 4 + 1) * 108 + dd];
            float4 a2 = *(const float4*)&s_ax[(rs * 4 + 2) * 108 + dd];
            float4 a3 = *(const float4*)&s_ax[(rs * 4 + 3) * 108 + dd];
            const float* wp = W_w + (size_t)dd * CATT + c;
            float4 w0 = *(const float4*)(wp);
            float4 w1 = *(const float4*)(wp + CATT);
            float4 w2 = *(const float4*)(wp + 2 * CATT);
            float4 w3 = *(const float4*)(wp + 3 * CATT);
            fma4(acc[0], a0.x, w0); fma4(acc[0], a0.y, w1); fma4(acc[0], a0.z, w2); fma4(acc[0], a0.w, w3);
            fma4(acc[1], a1.x, w0); fma4(acc[1], a1.y, w1); fma4(acc[1], a1.z, w2); fma4(acc[1], a1.w, w3);
            fma4(acc[2], a2.x, w0); fma4(acc[2], a2.y, w1); fma4(acc[2], a2.z, w2); fma4(acc[2], a2.w, w3);
            fma4(acc[3], a3.x, w0); fma4(acc[3], a3.y, w1); fma4(acc[3], a3.z, w2); fma4(acc[3], a3.w, w3);
        }
        float4 bias = *(const float4*)&W_b[c];
#pragma unroll
        for (int q = 0; q < 4; ++q) {
            float4 r;
            r.x = fmaxf(acc[q].x + bias.x, 0.f); r.y = fmaxf(acc[q].y + bias.y, 0.f);
            r.z = fmaxf(acc[q].z + bias.z, 0.f); r.w = fmaxf(acc[q].w + bias.w, 0.f);
            *(float4*)&go2[(size_t)(b * CL + i0 + rs * 4 + q) * CATT + c] = r;
        }
    }
}

// ---------------------------------------------------------------------------
// Kernel 8: out1 = masked mean of go2 (relu(relu)=relu); out = out1@clf_w+clf_b
// grid 32 blocks, 256 threads
// ---------------------------------------------------------------------------
__global__ __launch_bounds__(256) void k8_out(
    const float* __restrict__ go2, const float* __restrict__ amask,
    const float* __restrict__ aspwn, const float* __restrict__ clf_w,
    const float* __restrict__ clf_b, float* __restrict__ out)
{
    __shared__ float s_m[256];
    __shared__ float s_o[100];
    const int b = blockIdx.x, t = threadIdx.x;
    s_m[t] = amask[b * CL + t];
    __syncthreads();
    const float wn = aspwn[b];
    if (t < 100) {
        float a = 0.f;
        for (int l = 0; l < CL; ++l) a = fmaf(s_m[l], go2[(size_t)(b * CL + l) * CATT + t], a);
        s_o[t] = a / wn;
    }
    __syncthreads();
    if (t < 3) {
        float a = clf_b[t];
        for (int d = 0; d < 100; ++d) a = fmaf(s_o[d], clf_w[d * 3 + t], a);
        out[b * 3 + t] = a;
    }
}

// ---------------------------------------------------------------------------
extern "C" void kernel_launch(void* const* d_in, const int* in_sizes, int n_in,
                              void* d_out, int out_size, void* d_ws, size_t ws_size,
                              hipStream_t stream) {
    const float* seq     = (const float*)d_in[0];
    const int*   srcm    = (const int*)d_in[1];
    const float* amask   = (const float*)d_in[2];
    const float* shortm  = (const float*)d_in[3];
    const float* ln_a    = (const float*)d_in[4];
    const float* ln_b    = (const float*)d_in[5];
    const float* Wxx_w   = (const float*)d_in[6];
    const float* Wxx_b   = (const float*)d_in[7];
    const float* q_w     = (const float*)d_in[8];
    const float* q_b     = (const float*)d_in[9];
    const float* k_w     = (const float*)d_in[10];
    const float* k_b     = (const float*)d_in[11];
    const float* dense_w = (const float*)d_in[12];
    const float* dense_b = (const float*)d_in[13];
    const float* bias_m  = (const float*)d_in[14];
    const float* W_w     = (const float*)d_in[15];
    const float* W_b     = (const float*)d_in[16];
    const float* Wx_w    = (const float*)d_in[17];
    const float* Wx_b    = (const float*)d_in[18];
    const float* clf_w   = (const float*)d_in[19];
    const float* clf_b   = (const float*)d_in[20];
    float* out = (float*)d_out;

    float* ws   = (float*)d_ws;
    float* g    = ws;                    // 819200
    float* qt   = g + 819200;            // 819200
    float* ktb  = qt + 819200;           // 819200
    float* go1  = ktb + 819200;          // 819200
    float* go2  = go1 + 819200;          // 819200
    float* adjS = go2 + 819200;          // 2097152
    float* adjW = adjS + 2097152;        // 2097152
    float* asp  = adjW + 2097152;        // 640
    float* aspwn = asp + 640;            // 32
    float* t1   = aspwn + 32;            // 3200
    float* t2   = t1 + 3200;             // 3200
    float* gW2S = t2 + 3200;             // 8192

    hipLaunchKernelGGL(k1_ln_g,  dim3(256), dim3(256), 0, stream, seq, ln_a, ln_b, Wxx_w, Wxx_b, g);
    hipLaunchKernelGGL(k2_aspect, dim3(32), dim3(256), 0, stream, g, amask, dense_w, dense_b, asp, aspwn);
    hipLaunchKernelGGL(k3_qk,    dim3(256), dim3(256), 0, stream, g, q_w, q_b, k_w, k_b, qt, ktb);
    hipLaunchKernelGGL(k4_attn,  dim3(512), dim3(256), 0, stream, qt, ktb, asp, bias_m, srcm, shortm, Wx_w, adjS, adjW);
    hipLaunchKernelGGL(k5_gcn0,  dim3(256), dim3(256), 0, stream, adjS, g, W_w, W_b, go1);
    hipLaunchKernelGGL(k6_mid,   dim3(32),  dim3(256), 0, stream, go1, Wx_w, t1, t2, gW2S);
    hipLaunchKernelGGL(k7_gcn1,  dim3(256), dim3(256), 0, stream, adjW, go1, W_w, W_b, t1, t2, gW2S, Wx_b, go2);
    hipLaunchKernelGGL(k8_out,   dim3(32),  dim3(256), 0, stream, go2, amask, aspwn, clf_w, clf_b, out);
}

// Round 2
// 343.823 us; speedup vs baseline: 1.1638x; 1.1638x over previous
//
#include <hip/hip_runtime.h>
#include <math.h>

// Problem constants
constexpr int CB = 32;      // batch
constexpr int CL = 256;     // seq len
constexpr int CD = 768;     // bert dim
constexpr int CATT = 100;   // att dim
constexpr int CH = 5;       // heads
constexpr int CDK = 20;     // head dim

__device__ __forceinline__ void fma4(float4& a, float s, const float4& w) {
    a.x = fmaf(s, w.x, a.x);
    a.y = fmaf(s, w.y, a.y);
    a.z = fmaf(s, w.z, a.z);
    a.w = fmaf(s, w.w, a.w);
}

// ---------------------------------------------------------------------------
// Kernel 1 (fused): layernorm (ddof=1, eps on std) + g = xn@Wxx_w+Wxx_b
//                   + q = g@q_w+q_b, k = g@k_w+k_b  (written (B,H,L,DK))
// grid 256 blocks (32 rows each), 256 threads.
// NOTE: all inner GEMM loops use "#pragma unroll 2" — full unroll blew VGPR
// to 256 and spilled to scratch (r0: 26.8MB fetch / 34.8MB write on k3).
// ---------------------------------------------------------------------------
__global__ __launch_bounds__(256) void k1_fused(
    const float* __restrict__ x, const float* __restrict__ ln_a,
    const float* __restrict__ ln_b, const float* __restrict__ Wxx_w,
    const float* __restrict__ Wxx_b, const float* __restrict__ q_w,
    const float* __restrict__ q_b, const float* __restrict__ k_w,
    const float* __restrict__ k_b, float* __restrict__ g,
    float* __restrict__ qt, float* __restrict__ ktb)
{
    __shared__ float s_mean[32];
    __shared__ float s_rinv[32];
    __shared__ float s_xn[32 * 68];    // K-tile 32 rows x 64, stride 68
    __shared__ float s_gt[32 * 100];   // finished g tile for q/k phase

    const int t = threadIdx.x;
    const int r0 = blockIdx.x * 32;
    const int wid = t >> 6, lane = t & 63;

    // ---- stats: wave wid handles rows wid*8 .. wid*8+7 (wave-local reduce)
    for (int rr = wid * 8; rr < wid * 8 + 8; ++rr) {
        const float* xr = x + (size_t)(r0 + rr) * CD;
        float xv[12];
        float s = 0.f;
#pragma unroll
        for (int m = 0; m < 12; ++m) { xv[m] = xr[lane + 64 * m]; s += xv[m]; }
#pragma unroll
        for (int o = 32; o; o >>= 1) s += __shfl_xor(s, o);
        float mean = s * (1.0f / 768.0f);
        float sq = 0.f;
#pragma unroll
        for (int m = 0; m < 12; ++m) { float d = xv[m] - mean; sq = fmaf(d, d, sq); }
#pragma unroll
        for (int o = 32; o; o >>= 1) sq += __shfl_xor(sq, o);
        if (lane == 0) {
            s_mean[rr] = mean;
            s_rinv[rr] = 1.0f / (sqrtf(sq * (1.0f / 767.0f)) + 1e-6f);
        }
    }
    __syncthreads();

    const int cg = t % 25, rs = t / 25;
    const int c = cg * 4;
    float4 acc[4];
#pragma unroll
    for (int q = 0; q < 4; ++q) acc[q] = make_float4(0.f, 0.f, 0.f, 0.f);

    for (int kt = 0; kt < 12; ++kt) {
        // stage normalized K-tile into LDS
#pragma unroll
        for (int m = 0; m < 8; ++m) {
            int idx = t + 256 * m;
            int row = idx >> 6, kk = idx & 63;
            int k = kt * 64 + kk;
            float v = x[(size_t)(r0 + row) * CD + k];
            s_xn[row * 68 + kk] = fmaf(ln_a[k], (v - s_mean[row]) * s_rinv[row], ln_b[k]);
        }
        __syncthreads();
        if (t < 200) {
#pragma unroll 2
            for (int kk = 0; kk < 64; kk += 4) {
                float4 a0 = *(const float4*)&s_xn[(rs * 4 + 0) * 68 + kk];
                float4 a1 = *(const float4*)&s_xn[(rs * 4 + 1) * 68 + kk];
                float4 a2 = *(const float4*)&s_xn[(rs * 4 + 2) * 68 + kk];
                float4 a3 = *(const float4*)&s_xn[(rs * 4 + 3) * 68 + kk];
                const float* wp = Wxx_w + (size_t)(kt * 64 + kk) * CATT + c;
                float4 w0 = *(const float4*)(wp);
                float4 w1 = *(const float4*)(wp + CATT);
                float4 w2 = *(const float4*)(wp + 2 * CATT);
                float4 w3 = *(const float4*)(wp + 3 * CATT);
                fma4(acc[0], a0.x, w0); fma4(acc[0], a0.y, w1); fma4(acc[0], a0.z, w2); fma4(acc[0], a0.w, w3);
                fma4(acc[1], a1.x, w0); fma4(acc[1], a1.y, w1); fma4(acc[1], a1.z, w2); fma4(acc[1], a1.w, w3);
                fma4(acc[2], a2.x, w0); fma4(acc[2], a2.y, w1); fma4(acc[2], a2.z, w2); fma4(acc[2], a2.w, w3);
                fma4(acc[3], a3.x, w0); fma4(acc[3], a3.y, w1); fma4(acc[3], a3.z, w2); fma4(acc[3], a3.w, w3);
            }
        }
        __syncthreads();
    }
    if (t < 200) {
        float4 bias = *(const float4*)&Wxx_b[c];
#pragma unroll
        for (int q = 0; q < 4; ++q) {
            float4 r;
            r.x = acc[q].x + bias.x; r.y = acc[q].y + bias.y;
            r.z = acc[q].z + bias.z; r.w = acc[q].w + bias.w;
            *(float4*)&g[(size_t)(r0 + rs * 4 + q) * CATT + c] = r;
            *(float4*)&s_gt[(rs * 4 + q) * 100 + c] = r;
        }
    }
    __syncthreads();

    // ---- q/k phase from LDS g-tile
    if (t < 200) {
        const int h = c / CDK, d = c % CDK;
        for (int pass = 0; pass < 2; ++pass) {
            const float* W = pass ? k_w : q_w;
            const float* bb = pass ? k_b : q_b;
            float* outp = pass ? ktb : qt;
            float4 a2c[4];
#pragma unroll
            for (int q = 0; q < 4; ++q) a2c[q] = make_float4(0.f, 0.f, 0.f, 0.f);
#pragma unroll 2
            for (int k = 0; k < 100; k += 4) {
                float4 a0 = *(const float4*)&s_gt[(rs * 4 + 0) * 100 + k];
                float4 a1 = *(const float4*)&s_gt[(rs * 4 + 1) * 100 + k];
                float4 a2 = *(const float4*)&s_gt[(rs * 4 + 2) * 100 + k];
                float4 a3 = *(const float4*)&s_gt[(rs * 4 + 3) * 100 + k];
                const float* wp = W + (size_t)k * CATT + c;
                float4 w0 = *(const float4*)(wp);
                float4 w1 = *(const float4*)(wp + CATT);
                float4 w2 = *(const float4*)(wp + 2 * CATT);
                float4 w3 = *(const float4*)(wp + 3 * CATT);
                fma4(a2c[0], a0.x, w0); fma4(a2c[0], a0.y, w1); fma4(a2c[0], a0.z, w2); fma4(a2c[0], a0.w, w3);
                fma4(a2c[1], a1.x, w0); fma4(a2c[1], a1.y, w1); fma4(a2c[1], a1.z, w2); fma4(a2c[1], a1.w, w3);
                fma4(a2c[2], a2.x, w0); fma4(a2c[2], a2.y, w1); fma4(a2c[2], a2.z, w2); fma4(a2c[2], a2.w, w3);
                fma4(a2c[3], a3.x, w0); fma4(a2c[3], a3.y, w1); fma4(a2c[3], a3.z, w2); fma4(a2c[3], a3.w, w3);
            }
            float4 bias = *(const float4*)&bb[c];
#pragma unroll
            for (int q = 0; q < 4; ++q) {
                int row = r0 + rs * 4 + q;
                int bidx = row >> 8, l = row & 255;
                float4 r;
                r.x = a2c[q].x + bias.x; r.y = a2c[q].y + bias.y;
                r.z = a2c[q].z + bias.z; r.w = a2c[q].w + bias.w;
                *(float4*)&outp[((size_t)(bidx * CH + h) * CL + l) * CDK + d] = r;
            }
        }
    }
}

// ---------------------------------------------------------------------------
// Kernel 2: aspect pooling + asp = aspect @ dense_w + dense_b; also asp_wn
// grid 32 blocks (one per b), 256 threads
// ---------------------------------------------------------------------------
__global__ __launch_bounds__(256) void k2_aspect(
    const float* __restrict__ g, const float* __restrict__ amask,
    const float* __restrict__ dense_w, const float* __restrict__ dense_b,
    float* __restrict__ asp, float* __restrict__ aspwn)
{
    __shared__ float s_m[256];
    __shared__ float s_asp[100];
    __shared__ float red[4];
    const int b = blockIdx.x, t = threadIdx.x;
    const int wid = t >> 6, lane = t & 63;
    float mv = amask[b * CL + t];
    s_m[t] = mv;
    float s = mv;
#pragma unroll
    for (int o = 32; o; o >>= 1) s += __shfl_xor(s, o);
    if (lane == 0) red[wid] = s;
    __syncthreads();
    float wn = red[0] + red[1] + red[2] + red[3];
    if (t == 0) aspwn[b] = wn;
    if (t < 100) {
        float acc = 0.f;
        for (int l = 0; l < CL; ++l) acc = fmaf(s_m[l], g[(size_t)(b * CL + l) * CATT + t], acc);
        s_asp[t] = acc / wn;
    }
    __syncthreads();
    if (t < 20) {
        float a = dense_b[t];
        for (int d = 0; d < CATT; ++d) a = fmaf(s_asp[d], dense_w[d * CDK + t], a);
        asp[b * CDK + t] = a;
    }
}

// ---------------------------------------------------------------------------
// Kernel 4: scores + softmax, accumulate adjS = sum_h adj, adjW = sum_h adj*WaS[h]
// grid 32*16 blocks (b, 16-row i-chunk), 256 threads (thread = j)
// Restructured vs r0: shortm hoisted to regs (was re-read 5x), q-tile staged
// in LDS, all 16 row-sums go through ONE barrier per head (was 16).
// ---------------------------------------------------------------------------
__global__ __launch_bounds__(256) void k4_attn(
    const float* __restrict__ qt, const float* __restrict__ ktb,
    const float* __restrict__ asp, const float* __restrict__ bias_m,
    const int* __restrict__ src_mask, const float* __restrict__ shortm,
    const float* __restrict__ Wx_w, float* __restrict__ adjS,
    float* __restrict__ adjW)
{
    constexpr int ICH = 16;
    __shared__ float s_red[ICH * 4];
    __shared__ float s_was[5];
    __shared__ float s_aspb[20];
    __shared__ float s_q[ICH * CDK];   // 320 floats
    const int nch = CL / ICH;
    const int b = blockIdx.x / nch, ic = blockIdx.x % nch;
    const int t = threadIdx.x, lane = t & 63, wid = t >> 6;
    const int j = t;

    if (t < 5) {
        float s = 0.f;
        for (int k2 = 0; k2 < 5; ++k2) s += Wx_w[t * 5 + k2];
        s_was[t] = s;
    }
    if (t < 20) s_aspb[t] = asp[b * CDK + t];

    const bool masked = (src_mask[b * CL + j] == 0);
    const float bm = bias_m[0];
    const float rs20 = 0.223606797749978969f;  // 1/sqrt(20)

    float sm[ICH];
#pragma unroll
    for (int ii = 0; ii < ICH; ++ii)
        sm[ii] = shortm[(size_t)(b * CL + ic * ICH + ii) * CL + j];

    float accS[ICH], accW[ICH];
#pragma unroll
    for (int ii = 0; ii < ICH; ++ii) { accS[ii] = 0.f; accW[ii] = 0.f; }

    for (int h = 0; h < CH; ++h) {
        __syncthreads();   // protect s_q / s_red reuse (also covers init stores on h=0)
        {
            const size_t base = ((size_t)(b * CH + h) * CL + ic * ICH) * CDK;
            s_q[t] = qt[base + t];
            if (t < ICH * CDK - 256) s_q[256 + t] = qt[base + 256 + t];
        }
        float4 kr[5];
        const float* kp = ktb + ((size_t)(b * CH + h) * CL + j) * CDK;
#pragma unroll
        for (int m = 0; m < 5; ++m) kr[m] = *(const float4*)(kp + 4 * m);
        __syncthreads();

        const float was_h = s_was[h];
        float s = bm;
#pragma unroll
        for (int m = 0; m < 5; ++m) {
            s = fmaf(s_aspb[4 * m + 0], kr[m].x, s);
            s = fmaf(s_aspb[4 * m + 1], kr[m].y, s);
            s = fmaf(s_aspb[4 * m + 2], kr[m].z, s);
            s = fmaf(s_aspb[4 * m + 3], kr[m].w, s);
        }
        const float aspsc = tanhf(s);

        float pv[ICH];
#pragma unroll
        for (int ii = 0; ii < ICH; ++ii) {
            const float* qrow = &s_q[ii * CDK];
            float sc = 0.f;
#pragma unroll
            for (int m = 0; m < 5; ++m) {
                float4 q4 = *(const float4*)(qrow + 4 * m);
                sc = fmaf(q4.x, kr[m].x, sc);
                sc = fmaf(q4.y, kr[m].y, sc);
                sc = fmaf(q4.z, kr[m].z, sc);
                sc = fmaf(q4.w, kr[m].w, sc);
            }
            sc = fmaf(sc, rs20, aspsc) + sm[ii];
            float p = masked ? 0.f : __expf(sc);
            pv[ii] = p;
            float ssum = p;
#pragma unroll
            for (int o = 32; o; o >>= 1) ssum += __shfl_xor(ssum, o);
            if (lane == 0) s_red[ii * 4 + wid] = ssum;
        }
        __syncthreads();
#pragma unroll
        for (int ii = 0; ii < ICH; ++ii) {
            float tot = s_red[ii * 4 + 0] + s_red[ii * 4 + 1] +
                        s_red[ii * 4 + 2] + s_red[ii * 4 + 3];
            float pn = pv[ii] * __frcp_rn(tot);
            accS[ii] += pn;
            accW[ii] = fmaf(was_h, pn, accW[ii]);
        }
    }
#pragma unroll
    for (int ii = 0; ii < ICH; ++ii) {
        const int i = ic * ICH + ii;
        adjS[(size_t)(b * CL + i) * CL + j] = accS[ii];
        adjW[(size_t)(b * CL + i) * CL + j] = accW[ii];
    }
}

// ---------------------------------------------------------------------------
// Kernel 5: GCN layer 0: Ax = adjS @ g / H ; go1 = relu(Ax @ W_w + W_b)
// grid 32*8 blocks (b, 32-row i-chunk), 256 threads
// ---------------------------------------------------------------------------
__global__ __launch_bounds__(256) void k5_gcn0(
    const float* __restrict__ adjS, const float* __restrict__ g,
    const float* __restrict__ W_w, const float* __restrict__ W_b,
    float* __restrict__ go1)
{
    __shared__ float s_adj[32 * 260];
    __shared__ float s_ax[32 * 108];
    const int t = threadIdx.x;
    const int b = blockIdx.x >> 3, ic = blockIdx.x & 7;
    const int i0 = ic * 32;
    for (int idx = t; idx < 32 * 256; idx += 256) {
        int row = idx >> 8, jj = idx & 255;
        s_adj[row * 260 + jj] = adjS[(size_t)(b * CL + i0 + row) * CL + jj];
    }
    __syncthreads();
    const int cg = t % 25, rs = t / 25;
    const int c = cg * 4;
    if (t < 200) {
        float4 acc[4];
#pragma unroll
        for (int q = 0; q < 4; ++q) acc[q] = make_float4(0.f, 0.f, 0.f, 0.f);
#pragma unroll 2
        for (int jj = 0; jj < 256; jj += 4) {
            float4 a0 = *(const float4*)&s_adj[(rs * 4 + 0) * 260 + jj];
            float4 a1 = *(const float4*)&s_adj[(rs * 4 + 1) * 260 + jj];
            float4 a2 = *(const float4*)&s_adj[(rs * 4 + 2) * 260 + jj];
            float4 a3 = *(const float4*)&s_adj[(rs * 4 + 3) * 260 + jj];
            const float* gp = g + (size_t)(b * CL + jj) * CATT + c;
            float4 g0 = *(const float4*)(gp);
            float4 g1 = *(const float4*)(gp + CATT);
            float4 g2 = *(const float4*)(gp + 2 * CATT);
            float4 g3 = *(const float4*)(gp + 3 * CATT);
            fma4(acc[0], a0.x, g0); fma4(acc[0], a0.y, g1); fma4(acc[0], a0.z, g2); fma4(acc[0], a0.w, g3);
            fma4(acc[1], a1.x, g0); fma4(acc[1], a1.y, g1); fma4(acc[1], a1.z, g2); fma4(acc[1], a1.w, g3);
            fma4(acc[2], a2.x, g0); fma4(acc[2], a2.y, g1); fma4(acc[2], a2.z, g2); fma4(acc[2], a2.w, g3);
            fma4(acc[3], a3.x, g0); fma4(acc[3], a3.y, g1); fma4(acc[3], a3.z, g2); fma4(acc[3], a3.w, g3);
        }
#pragma unroll
        for (int q = 0; q < 4; ++q) {
            float4 r;
            r.x = acc[q].x * 0.2f; r.y = acc[q].y * 0.2f;
            r.z = acc[q].z * 0.2f; r.w = acc[q].w * 0.2f;
            *(float4*)&s_ax[(rs * 4 + q) * 108 + c] = r;
        }
    }
    __syncthreads();
    if (t < 200) {
        float4 acc[4];
#pragma unroll
        for (int q = 0; q < 4; ++q) acc[q] = make_float4(0.f, 0.f, 0.f, 0.f);
#pragma unroll 2
        for (int dd = 0; dd < 100; dd += 4) {
            float4 a0 = *(const float4*)&s_ax[(rs * 4 + 0) * 108 + dd];
            float4 a1 = *(const float4*)&s_ax[(rs * 4 + 1) * 108 + dd];
            float4 a2 = *(const float4*)&s_ax[(rs * 4 + 2) * 108 + dd];
            float4 a3 = *(const float4*)&s_ax[(rs * 4 + 3) * 108 + dd];
            const float* wp = W_w + (size_t)dd * CATT + c;
            float4 w0 = *(const float4*)(wp);
            float4 w1 = *(const float4*)(wp + CATT);
            float4 w2 = *(const float4*)(wp + 2 * CATT);
            float4 w3 = *(const float4*)(wp + 3 * CATT);
            fma4(acc[0], a0.x, w0); fma4(acc[0], a0.y, w1); fma4(acc[0], a0.z, w2); fma4(acc[0], a0.w, w3);
            fma4(acc[1], a1.x, w0); fma4(acc[1], a1.y, w1); fma4(acc[1], a1.z, w2); fma4(acc[1], a1.w, w3);
            fma4(acc[2], a2.x, w0); fma4(acc[2], a2.y, w1); fma4(acc[2], a2.z, w2); fma4(acc[2], a2.w, w3);
            fma4(acc[3], a3.x, w0); fma4(acc[3], a3.y, w1); fma4(acc[3], a3.z, w2); fma4(acc[3], a3.w, w3);
        }
        float4 bias = *(const float4*)&W_b[c];
#pragma unroll
        for (int q = 0; q < 4; ++q) {
            float4 r;
            r.x = fmaxf(acc[q].x + bias.x, 0.f); r.y = fmaxf(acc[q].y + bias.y, 0.f);
            r.z = fmaxf(acc[q].z + bias.z, 0.f); r.w = fmaxf(acc[q].w + bias.w, 0.f);
            *(float4*)&go1[(size_t)(b * CL + i0 + rs * 4 + q) * CATT + c] = r;
        }
    }
}

// ---------------------------------------------------------------------------
// Kernel 6: per-b rank-1 pieces: gW2S[b,i], t1[b,d], t2[b,d]
// grid 32 blocks, 256 threads
// ---------------------------------------------------------------------------
__global__ __launch_bounds__(256) void k6_mid(
    const float* __restrict__ go1, const float* __restrict__ Wx_w,
    float* __restrict__ t1, float* __restrict__ t2, float* __restrict__ gW2S)
{
    __shared__ float s_w1[100];
    __shared__ float s_w2[100];
    __shared__ float s_g1[256];
    const int b = blockIdx.x, t = threadIdx.x;
    if (t < 100) {
        float a = 0.f, c2 = 0.f;
#pragma unroll
        for (int h = 0; h < 5; ++h) {
            a += Wx_w[(5 + t) * 5 + h];
            c2 += Wx_w[(105 + t) * 5 + h];
        }
        s_w1[t] = a; s_w2[t] = c2;
    }
    __syncthreads();
    {
        const float* gp = go1 + (size_t)(b * CL + t) * CATT;
        float a = 0.f, c2 = 0.f;
        for (int e = 0; e < 100; ++e) {
            float v = gp[e];
            a = fmaf(v, s_w1[e], a);
            c2 = fmaf(v, s_w2[e], c2);
        }
        s_g1[t] = a;
        gW2S[b * CL + t] = c2;
    }
    __syncthreads();
    if (t < 100) {
        float a = 0.f, s2 = 0.f;
        for (int jj = 0; jj < 256; ++jj) {
            float v = go1[(size_t)(b * CL + jj) * CATT + t];
            a = fmaf(s_g1[jj], v, a);
            s2 += v;
        }
        t1[b * CATT + t] = a;
        t2[b * CATT + t] = s2;
    }
}

// ---------------------------------------------------------------------------
// Kernel 7: GCN layer 1: Ax2 = (adjW@go1 + t1 + (gW2S[i]+WxbS)*t2)/H;
//           go2 = relu(Ax2 @ W_w + W_b)
// ---------------------------------------------------------------------------
__global__ __launch_bounds__(256) void k7_gcn1(
    const float* __restrict__ adjW, const float* __restrict__ go1,
    const float* __restrict__ W_w, const float* __restrict__ W_b,
    const float* __restrict__ t1, const float* __restrict__ t2,
    const float* __restrict__ gW2S, const float* __restrict__ Wx_b,
    float* __restrict__ go2)
{
    __shared__ float s_adj[32 * 260];
    __shared__ float s_ax[32 * 108];
    const int t = threadIdx.x;
    const int b = blockIdx.x >> 3, ic = blockIdx.x & 7;
    const int i0 = ic * 32;
    for (int idx = t; idx < 32 * 256; idx += 256) {
        int row = idx >> 8, jj = idx & 255;
        s_adj[row * 260 + jj] = adjW[(size_t)(b * CL + i0 + row) * CL + jj];
    }
    __syncthreads();
    const int cg = t % 25, rs = t / 25;
    const int c = cg * 4;
    if (t < 200) {
        float4 acc[4];
#pragma unroll
        for (int q = 0; q < 4; ++q) acc[q] = make_float4(0.f, 0.f, 0.f, 0.f);
#pragma unroll 2
        for (int jj = 0; jj < 256; jj += 4) {
            float4 a0 = *(const float4*)&s_adj[(rs * 4 + 0) * 260 + jj];
            float4 a1 = *(const float4*)&s_adj[(rs * 4 + 1) * 260 + jj];
            float4 a2 = *(const float4*)&s_adj[(rs * 4 + 2) * 260 + jj];
            float4 a3 = *(const float4*)&s_adj[(rs * 4 + 3) * 260 + jj];
            const float* gp = go1 + (size_t)(b * CL + jj) * CATT + c;
            float4 g0 = *(const float4*)(gp);
            float4 g1 = *(const float4*)(gp + CATT);
            float4 g2 = *(const float4*)(gp + 2 * CATT);
            float4 g3 = *(const float4*)(gp + 3 * CATT);
            fma4(acc[0], a0.x, g0); fma4(acc[0], a0.y, g1); fma4(acc[0], a0.z, g2); fma4(acc[0], a0.w, g3);
            fma4(acc[1], a1.x, g0); fma4(acc[1], a1.y, g1); fma4(acc[1], a1.z, g2); fma4(acc[1], a1.w, g3);
            fma4(acc[2], a2.x, g0); fma4(acc[2], a2.y, g1); fma4(acc[2], a2.z, g2); fma4(acc[2], a2.w, g3);
            fma4(acc[3], a3.x, g0); fma4(acc[3], a3.y, g1); fma4(acc[3], a3.z, g2); fma4(acc[3], a3.w, g3);
        }
        float wxbs = Wx_b[0] + Wx_b[1] + Wx_b[2] + Wx_b[3] + Wx_b[4];
        float4 t1v = *(const float4*)&t1[b * CATT + c];
        float4 t2v = *(const float4*)&t2[b * CATT + c];
#pragma unroll
        for (int q = 0; q < 4; ++q) {
            int i = i0 + rs * 4 + q;
            float gw2 = gW2S[b * CL + i] + wxbs;
            float4 r;
            r.x = (acc[q].x + t1v.x + gw2 * t2v.x) * 0.2f;
            r.y = (acc[q].y + t1v.y + gw2 * t2v.y) * 0.2f;
            r.z = (acc[q].z + t1v.z + gw2 * t2v.z) * 0.2f;
            r.w = (acc[q].w + t1v.w + gw2 * t2v.w) * 0.2f;
            *(float4*)&s_ax[(rs * 4 + q) * 108 + c] = r;
        }
    }
    __syncthreads();
    if (t < 200) {
        float4 acc[4];
#pragma unroll
        for (int q = 0; q < 4; ++q) acc[q] = make_float4(0.f, 0.f, 0.f, 0.f);
#pragma unroll 2
        for (int dd = 0; dd < 100; dd += 4) {
            float4 a0 = *(const float4*)&s_ax[(rs * 4 + 0) * 108 + dd];
            float4 a1 = *(const float4*)&s_ax[(rs * 4 + 1) * 108 + dd];
            float4 a2 = *(const float4*)&s_ax[(rs * 4 + 2) * 108 + dd];
            float4 a3 = *(const float4*)&s_ax[(rs * 4 + 3) * 108 + dd];
            const float* wp = W_w + (size_t)dd * CATT + c;
            float4 w0 = *(const float4*)(wp);
            float4 w1 = *(const float4*)(wp + CATT);
            float4 w2 = *(const float4*)(wp + 2 * CATT);
            float4 w3 = *(const float4*)(wp + 3 * CATT);
            fma4(acc[0], a0.x, w0); fma4(acc[0], a0.y, w1); fma4(acc[0], a0.z, w2); fma4(acc[0], a0.w, w3);
            fma4(acc[1], a1.x, w0); fma4(acc[1], a1.y, w1); fma4(acc[1], a1.z, w2); fma4(acc[1], a1.w, w3);
            fma4(acc[2], a2.x, w0); fma4(acc[2], a2.y, w1); fma4(acc[2], a2.z, w2); fma4(acc[2], a2.w, w3);
            fma4(acc[3], a3.x, w0); fma4(acc[3], a3.y, w1); fma4(acc[3], a3.z, w2); fma4(acc[3], a3.w, w3);
        }
        float4 bias = *(const float4*)&W_b[c];
#pragma unroll
        for (int q = 0; q < 4; ++q) {
            float4 r;
            r.x = fmaxf(acc[q].x + bias.x, 0.f); r.y = fmaxf(acc[q].y + bias.y, 0.f);
            r.z = fmaxf(acc[q].z + bias.z, 0.f); r.w = fmaxf(acc[q].w + bias.w, 0.f);
            *(float4*)&go2[(size_t)(b * CL + i0 + rs * 4 + q) * CATT + c] = r;
        }
    }
}

// ---------------------------------------------------------------------------
// Kernel 8: out1 = masked mean of go2 (relu(relu)=relu); out = out1@clf_w+clf_b
// grid 32 blocks, 256 threads
// ---------------------------------------------------------------------------
__global__ __launch_bounds__(256) void k8_out(
    const float* __restrict__ go2, const float* __restrict__ amask,
    const float* __restrict__ aspwn, const float* __restrict__ clf_w,
    const float* __restrict__ clf_b, float* __restrict__ out)
{
    __shared__ float s_m[256];
    __shared__ float s_o[100];
    const int b = blockIdx.x, t = threadIdx.x;
    s_m[t] = amask[b * CL + t];
    __syncthreads();
    const float wn = aspwn[b];
    if (t < 100) {
        float a = 0.f;
        for (int l = 0; l < CL; ++l) a = fmaf(s_m[l], go2[(size_t)(b * CL + l) * CATT + t], a);
        s_o[t] = a / wn;
    }
    __syncthreads();
    if (t < 3) {
        float a = clf_b[t];
        for (int d = 0; d < 100; ++d) a = fmaf(s_o[d], clf_w[d * 3 + t], a);
        out[b * 3 + t] = a;
    }
}

// ---------------------------------------------------------------------------
extern "C" void kernel_launch(void* const* d_in, const int* in_sizes, int n_in,
                              void* d_out, int out_size, void* d_ws, size_t ws_size,
                              hipStream_t stream) {
    const float* seq     = (const float*)d_in[0];
    const int*   srcm    = (const int*)d_in[1];
    const float* amask   = (const float*)d_in[2];
    const float* shortm  = (const float*)d_in[3];
    const float* ln_a    = (const float*)d_in[4];
    const float* ln_b    = (const float*)d_in[5];
    const float* Wxx_w   = (const float*)d_in[6];
    const float* Wxx_b   = (const float*)d_in[7];
    const float* q_w     = (const float*)d_in[8];
    const float* q_b     = (const float*)d_in[9];
    const float* k_w     = (const float*)d_in[10];
    const float* k_b     = (const float*)d_in[11];
    const float* dense_w = (const float*)d_in[12];
    const float* dense_b = (const float*)d_in[13];
    const float* bias_m  = (const float*)d_in[14];
    const float* W_w     = (const float*)d_in[15];
    const float* W_b     = (const float*)d_in[16];
    const float* Wx_w    = (const float*)d_in[17];
    const float* Wx_b    = (const float*)d_in[18];
    const float* clf_w   = (const float*)d_in[19];
    const float* clf_b   = (const float*)d_in[20];
    float* out = (float*)d_out;

    float* ws   = (float*)d_ws;
    float* g    = ws;                    // 819200
    float* qt   = g + 819200;            // 819200
    float* ktb  = qt + 819200;           // 819200
    float* go1  = ktb + 819200;          // 819200
    float* go2  = go1 + 819200;          // 819200
    float* adjS = go2 + 819200;          // 2097152
    float* adjW = adjS + 2097152;        // 2097152
    float* asp  = adjW + 2097152;        // 640
    float* aspwn = asp + 640;            // 32
    float* t1   = aspwn + 32;            // 3200
    float* t2   = t1 + 3200;             // 3200
    float* gW2S = t2 + 3200;             // 8192

    hipLaunchKernelGGL(k1_fused, dim3(256), dim3(256), 0, stream, seq, ln_a, ln_b,
                       Wxx_w, Wxx_b, q_w, q_b, k_w, k_b, g, qt, ktb);
    hipLaunchKernelGGL(k2_aspect, dim3(32), dim3(256), 0, stream, g, amask, dense_w, dense_b, asp, aspwn);
    hipLaunchKernelGGL(k4_attn,  dim3(512), dim3(256), 0, stream, qt, ktb, asp, bias_m, srcm, shortm, Wx_w, adjS, adjW);
    hipLaunchKernelGGL(k5_gcn0,  dim3(256), dim3(256), 0, stream, adjS, g, W_w, W_b, go1);
    hipLaunchKernelGGL(k6_mid,   dim3(32),  dim3(256), 0, stream, go1, Wx_w, t1, t2, gW2S);
    hipLaunchKernelGGL(k7_gcn1,  dim3(256), dim3(256), 0, stream, adjW, go1, W_w, W_b, t1, t2, gW2S, Wx_b, go2);
    hipLaunchKernelGGL(k8_out,   dim3(32),  dim3(256), 0, stream, go2, amask, aspwn, clf_w, clf_b, out);
}

// Round 3
// 259.124 us; speedup vs baseline: 1.5442x; 1.3269x over previous
//
#include <hip/hip_runtime.h>
#include <math.h>

constexpr int CL = 256;
constexpr int CD = 768;
constexpr int CATT = 100;
constexpr int CH = 5;
constexpr int CDK = 20;

__device__ __forceinline__ void fma4(float4& a, float s, const float4& w) {
    a.x = fmaf(s, w.x, a.x);
    a.y = fmaf(s, w.y, a.y);
    a.z = fmaf(s, w.z, a.z);
    a.w = fmaf(s, w.w, a.w);
}

// ---------------------------------------------------------------------------
// Kernel 1 (fused): layernorm + g = xn@Wxx_w+b + q/k GEMMs + masked aspect
// pooling via atomicAdd. 512 blocks (16-row tiles), 256 threads, LDS-staged W.
// ---------------------------------------------------------------------------
__global__ __launch_bounds__(256) void k1_fused(
    const float* __restrict__ x, const float* __restrict__ ln_a,
    const float* __restrict__ ln_b, const float* __restrict__ Wxx_w,
    const float* __restrict__ Wxx_b, const float* __restrict__ q_w,
    const float* __restrict__ q_b, const float* __restrict__ k_w,
    const float* __restrict__ k_b, const float* __restrict__ amask,
    float* __restrict__ g, float* __restrict__ qt, float* __restrict__ ktb,
    float* __restrict__ aspect_raw)
{
    __shared__ float s_mean[16], s_rinv[16];
    __shared__ float s_xn[16 * 68];
    __shared__ float s_w[100 * 104];
    __shared__ float s_gt[16 * 100];

    const int t = threadIdx.x;
    const int r0 = blockIdx.x * 16;
    const int wid = t >> 6, lane = t & 63;

    for (int rr = wid * 4; rr < wid * 4 + 4; ++rr) {
        const float* xr = x + (size_t)(r0 + rr) * CD;
        float xv[12];
        float s = 0.f;
#pragma unroll
        for (int m = 0; m < 12; ++m) { xv[m] = xr[lane + 64 * m]; s += xv[m]; }
#pragma unroll
        for (int o = 32; o; o >>= 1) s += __shfl_xor(s, o);
        float mean = s * (1.0f / 768.0f);
        float sq = 0.f;
#pragma unroll
        for (int m = 0; m < 12; ++m) { float d = xv[m] - mean; sq = fmaf(d, d, sq); }
#pragma unroll
        for (int o = 32; o; o >>= 1) sq += __shfl_xor(sq, o);
        if (lane == 0) {
            s_mean[rr] = mean;
            s_rinv[rr] = 1.0f / (sqrtf(sq * (1.0f / 767.0f)) + 1e-6f);
        }
    }
    __syncthreads();

    const int cg = t % 25, rg = t / 25;
    const int c = cg * 4;
    float4 acc0 = make_float4(0.f, 0.f, 0.f, 0.f);
    float4 acc1 = make_float4(0.f, 0.f, 0.f, 0.f);

    for (int kt = 0; kt < 12; ++kt) {
#pragma unroll
        for (int m = 0; m < 4; ++m) {
            int idx = t + 256 * m;
            int row = idx >> 6, kk = idx & 63;
            int k = kt * 64 + kk;
            float v = x[(size_t)(r0 + row) * CD + k];
            s_xn[row * 68 + kk] = fmaf(ln_a[k], (v - s_mean[row]) * s_rinv[row], ln_b[k]);
        }
        const float4* wsrc = (const float4*)Wxx_w + (size_t)kt * 1600;
        for (int i = t; i < 1600; i += 256) {
            int row = i / 25, c4 = i % 25;
            *(float4*)&s_w[row * 104 + c4 * 4] = wsrc[i];
        }
        __syncthreads();
        if (t < 200) {
#pragma unroll 2
            for (int kk = 0; kk < 64; kk += 4) {
                float4 a0 = *(const float4*)&s_xn[(rg * 2 + 0) * 68 + kk];
                float4 a1 = *(const float4*)&s_xn[(rg * 2 + 1) * 68 + kk];
                float4 w0 = *(const float4*)&s_w[(kk + 0) * 104 + c];
                float4 w1 = *(const float4*)&s_w[(kk + 1) * 104 + c];
                float4 w2 = *(const float4*)&s_w[(kk + 2) * 104 + c];
                float4 w3 = *(const float4*)&s_w[(kk + 3) * 104 + c];
                fma4(acc0, a0.x, w0); fma4(acc0, a0.y, w1); fma4(acc0, a0.z, w2); fma4(acc0, a0.w, w3);
                fma4(acc1, a1.x, w0); fma4(acc1, a1.y, w1); fma4(acc1, a1.z, w2); fma4(acc1, a1.w, w3);
            }
        }
        __syncthreads();
    }
    if (t < 200) {
        float4 bias = *(const float4*)&Wxx_b[c];
        float4 rr0, rr1;
        rr0.x = acc0.x + bias.x; rr0.y = acc0.y + bias.y; rr0.z = acc0.z + bias.z; rr0.w = acc0.w + bias.w;
        rr1.x = acc1.x + bias.x; rr1.y = acc1.y + bias.y; rr1.z = acc1.z + bias.z; rr1.w = acc1.w + bias.w;
        float4 rv[2] = { rr0, rr1 };
#pragma unroll
        for (int q = 0; q < 2; ++q) {
            int row = r0 + rg * 2 + q;
            *(float4*)&g[(size_t)row * CATT + c] = rv[q];
            *(float4*)&s_gt[(rg * 2 + q) * 100 + c] = rv[q];
            float m = amask[row];
            if (m != 0.f) {
                int b = row >> 8;
                atomicAdd(&aspect_raw[b * CATT + c + 0], m * rv[q].x);
                atomicAdd(&aspect_raw[b * CATT + c + 1], m * rv[q].y);
                atomicAdd(&aspect_raw[b * CATT + c + 2], m * rv[q].z);
                atomicAdd(&aspect_raw[b * CATT + c + 3], m * rv[q].w);
            }
        }
    }
    __syncthreads();

    for (int pass = 0; pass < 2; ++pass) {
        const float4* ws4 = (const float4*)(pass ? k_w : q_w);
        for (int i = t; i < 2500; i += 256) {
            int row = i / 25, c4 = i % 25;
            *(float4*)&s_w[row * 104 + c4 * 4] = ws4[i];
        }
        __syncthreads();
        if (t < 200) {
            const float* bb = pass ? k_b : q_b;
            float* outp = pass ? ktb : qt;
            float4 b0 = make_float4(0.f, 0.f, 0.f, 0.f);
            float4 b1 = make_float4(0.f, 0.f, 0.f, 0.f);
#pragma unroll 2
            for (int k = 0; k < 100; k += 4) {
                float4 a0 = *(const float4*)&s_gt[(rg * 2 + 0) * 100 + k];
                float4 a1 = *(const float4*)&s_gt[(rg * 2 + 1) * 100 + k];
                float4 w0 = *(const float4*)&s_w[(k + 0) * 104 + c];
                float4 w1 = *(const float4*)&s_w[(k + 1) * 104 + c];
                float4 w2 = *(const float4*)&s_w[(k + 2) * 104 + c];
                float4 w3 = *(const float4*)&s_w[(k + 3) * 104 + c];
                fma4(b0, a0.x, w0); fma4(b0, a0.y, w1); fma4(b0, a0.z, w2); fma4(b0, a0.w, w3);
                fma4(b1, a1.x, w0); fma4(b1, a1.y, w1); fma4(b1, a1.z, w2); fma4(b1, a1.w, w3);
            }
            float4 bias = *(const float4*)&bb[c];
            b0.x += bias.x; b0.y += bias.y; b0.z += bias.z; b0.w += bias.w;
            b1.x += bias.x; b1.y += bias.y; b1.z += bias.z; b1.w += bias.w;
            const int h = c / CDK, d = c % CDK;
            float4 rv[2] = { b0, b1 };
#pragma unroll
            for (int q = 0; q < 2; ++q) {
                int row = r0 + rg * 2 + q;
                int bidx = row >> 8, l = row & 255;
                *(float4*)&outp[((size_t)(bidx * CH + h) * CL + l) * CDK + d] = rv[q];
            }
        }
        __syncthreads();
    }
}

// ---------------------------------------------------------------------------
__global__ __launch_bounds__(256) void k2_small(
    const float* __restrict__ aspect_raw, const float* __restrict__ amask,
    const float* __restrict__ dense_w, const float* __restrict__ dense_b,
    float* __restrict__ asp, float* __restrict__ aspwn)
{
    __shared__ float red[4];
    const int b = blockIdx.x, t = threadIdx.x;
    const int wid = t >> 6, lane = t & 63;
    float s = amask[b * CL + t];
#pragma unroll
    for (int o = 32; o; o >>= 1) s += __shfl_xor(s, o);
    if (lane == 0) red[wid] = s;
    __syncthreads();
    float wn = red[0] + red[1] + red[2] + red[3];
    if (t == 0) aspwn[b] = wn;
    if (t < 20) {
        float a = dense_b[t];
        float rwn = 1.f / wn;
        for (int d = 0; d < CATT; ++d)
            a = fmaf(aspect_raw[b * CATT + d] * rwn, dense_w[d * CDK + t], a);
        asp[b * CDK + t] = a;
    }
}

// ---------------------------------------------------------------------------
// Fused softmax + GCN0 + rank-1 reductions. 512 blocks (b, 16-row chunk).
// ---------------------------------------------------------------------------
__global__ __launch_bounds__(256) void k45_attn_gcn0(
    const float* __restrict__ qt, const float* __restrict__ ktb,
    const float* __restrict__ asp, const float* __restrict__ bias_m,
    const int* __restrict__ src_mask, const float* __restrict__ shortm,
    const float* __restrict__ Wx_w, const float* __restrict__ g,
    const float* __restrict__ W_w, const float* __restrict__ W_b,
    float* __restrict__ adjW, float* __restrict__ go1,
    float* __restrict__ t1, float* __restrict__ t2, float* __restrict__ gW2S)
{
    constexpr int ICH = 16;
    __shared__ float s_adj[16 * 260];
    __shared__ float s_b[100 * 104];
    __shared__ float s_ax[16 * 108];
    __shared__ float s_q[ICH * CDK];
    __shared__ float s_red[ICH * 4];
    __shared__ float s_was[5];
    __shared__ float s_aspb[20];
    __shared__ float s_w1[100], s_w2[100];
    __shared__ float s_g1row[16];

    const int b = blockIdx.x >> 4, ic = blockIdx.x & 15;
    const int i0 = ic * 16;
    const int t = threadIdx.x, lane = t & 63, wid = t >> 6;
    const int j = t;

    if (t < 5) {
        float s = 0.f;
        for (int k2 = 0; k2 < 5; ++k2) s += Wx_w[t * 5 + k2];
        s_was[t] = s;
    }
    if (t < 20) s_aspb[t] = asp[b * CDK + t];
    if (t < 100) {
        float a = 0.f, c2 = 0.f;
#pragma unroll
        for (int h = 0; h < 5; ++h) {
            a += Wx_w[(5 + t) * 5 + h];
            c2 += Wx_w[(105 + t) * 5 + h];
        }
        s_w1[t] = a; s_w2[t] = c2;
    }

    const bool masked = (src_mask[b * CL + j] == 0);
    const float bm = bias_m[0];
    const float rs20 = 0.223606797749978969f;

    float sm[ICH];
#pragma unroll
    for (int ii = 0; ii < ICH; ++ii)
        sm[ii] = shortm[(size_t)(b * CL + i0 + ii) * CL + j];

    float accS[ICH], accW[ICH];
#pragma unroll
    for (int ii = 0; ii < ICH; ++ii) { accS[ii] = 0.f; accW[ii] = 0.f; }

    for (int h = 0; h < CH; ++h) {
        __syncthreads();
        {
            const size_t base = ((size_t)(b * CH + h) * CL + i0) * CDK;
            s_q[t] = qt[base + t];
            if (t < ICH * CDK - 256) s_q[256 + t] = qt[base + 256 + t];
        }
        float4 kr[5];
        const float* kp = ktb + ((size_t)(b * CH + h) * CL + j) * CDK;
#pragma unroll
        for (int m = 0; m < 5; ++m) kr[m] = *(const float4*)(kp + 4 * m);
        __syncthreads();

        const float was_h = s_was[h];
        float s = bm;
#pragma unroll
        for (int m = 0; m < 5; ++m) {
            s = fmaf(s_aspb[4 * m + 0], kr[m].x, s);
            s = fmaf(s_aspb[4 * m + 1], kr[m].y, s);
            s = fmaf(s_aspb[4 * m + 2], kr[m].z, s);
            s = fmaf(s_aspb[4 * m + 3], kr[m].w, s);
        }
        const float aspsc = tanhf(s);

        float pv[ICH];
#pragma unroll
        for (int ii = 0; ii < ICH; ++ii) {
            const float* qrow = &s_q[ii * CDK];
            float sc = 0.f;
#pragma unroll
            for (int m = 0; m < 5; ++m) {
                float4 q4 = *(const float4*)(qrow + 4 * m);
                sc = fmaf(q4.x, kr[m].x, sc);
                sc = fmaf(q4.y, kr[m].y, sc);
                sc = fmaf(q4.z, kr[m].z, sc);
                sc = fmaf(q4.w, kr[m].w, sc);
            }
            sc = fmaf(sc, rs20, aspsc) + sm[ii];
            float p = masked ? 0.f : __expf(sc);
            pv[ii] = p;
            float ssum = p;
#pragma unroll
            for (int o = 32; o; o >>= 1) ssum += __shfl_xor(ssum, o);
            if (lane == 0) s_red[ii * 4 + wid] = ssum;
        }
        __syncthreads();
#pragma unroll
        for (int ii = 0; ii < ICH; ++ii) {
            float tot = s_red[ii * 4 + 0] + s_red[ii * 4 + 1] +
                        s_red[ii * 4 + 2] + s_red[ii * 4 + 3];
            float pn = pv[ii] * __frcp_rn(tot);
            accS[ii] += pn;
            accW[ii] = fmaf(was_h, pn, accW[ii]);
        }
    }

#pragma unroll
    for (int ii = 0; ii < ICH; ++ii) {
        adjW[(size_t)(b * CL + i0 + ii) * CL + j] = accW[ii];
        s_adj[ii * 260 + j] = accS[ii];
    }
    __syncthreads();

    const int cg = t % 25, rg = t / 25;
    const int c = cg * 4;
    float4 acc0 = make_float4(0.f, 0.f, 0.f, 0.f);
    float4 acc1 = make_float4(0.f, 0.f, 0.f, 0.f);
    for (int jt = 0; jt < 4; ++jt) {
        const float4* src = (const float4*)g + (size_t)(b * CL + jt * 64) * 25;
        for (int i = t; i < 1600; i += 256) {
            int row = i / 25, c4 = i % 25;
            *(float4*)&s_b[row * 104 + c4 * 4] = src[i];
        }
        __syncthreads();
        if (t < 200) {
#pragma unroll 2
            for (int kk = 0; kk < 64; kk += 4) {
                float4 a0 = *(const float4*)&s_adj[(rg * 2 + 0) * 260 + jt * 64 + kk];
                float4 a1 = *(const float4*)&s_adj[(rg * 2 + 1) * 260 + jt * 64 + kk];
                float4 w0 = *(const float4*)&s_b[(kk + 0) * 104 + c];
                float4 w1 = *(const float4*)&s_b[(kk + 1) * 104 + c];
                float4 w2 = *(const float4*)&s_b[(kk + 2) * 104 + c];
                float4 w3 = *(const float4*)&s_b[(kk + 3) * 104 + c];
                fma4(acc0, a0.x, w0); fma4(acc0, a0.y, w1); fma4(acc0, a0.z, w2); fma4(acc0, a0.w, w3);
                fma4(acc1, a1.x, w0); fma4(acc1, a1.y, w1); fma4(acc1, a1.z, w2); fma4(acc1, a1.w, w3);
            }
        }
        __syncthreads();
    }
    if (t < 200) {
        float4 r;
        r.x = acc0.x * 0.2f; r.y = acc0.y * 0.2f; r.z = acc0.z * 0.2f; r.w = acc0.w * 0.2f;
        *(float4*)&s_ax[(rg * 2 + 0) * 108 + c] = r;
        r.x = acc1.x * 0.2f; r.y = acc1.y * 0.2f; r.z = acc1.z * 0.2f; r.w = acc1.w * 0.2f;
        *(float4*)&s_ax[(rg * 2 + 1) * 108 + c] = r;
    }
    {
        const float4* ws4 = (const float4*)W_w;
        for (int i = t; i < 2500; i += 256) {
            int row = i / 25, c4 = i % 25;
            *(float4*)&s_b[row * 104 + c4 * 4] = ws4[i];
        }
    }
    __syncthreads();

    float4 o0 = make_float4(0.f, 0.f, 0.f, 0.f);
    float4 o1 = make_float4(0.f, 0.f, 0.f, 0.f);
    if (t < 200) {
#pragma unroll 2
        for (int k = 0; k < 100; k += 4) {
            float4 a0 = *(const float4*)&s_ax[(rg * 2 + 0) * 108 + k];
            float4 a1 = *(const float4*)&s_ax[(rg * 2 + 1) * 108 + k];
            float4 w0 = *(const float4*)&s_b[(k + 0) * 104 + c];
            float4 w1 = *(const float4*)&s_b[(k + 1) * 104 + c];
            float4 w2 = *(const float4*)&s_b[(k + 2) * 104 + c];
            float4 w3 = *(const float4*)&s_b[(k + 3) * 104 + c];
            fma4(o0, a0.x, w0); fma4(o0, a0.y, w1); fma4(o0, a0.z, w2); fma4(o0, a0.w, w3);
            fma4(o1, a1.x, w0); fma4(o1, a1.y, w1); fma4(o1, a1.z, w2); fma4(o1, a1.w, w3);
        }
        float4 bias = *(const float4*)&W_b[c];
        o0.x = fmaxf(o0.x + bias.x, 0.f); o0.y = fmaxf(o0.y + bias.y, 0.f);
        o0.z = fmaxf(o0.z + bias.z, 0.f); o0.w = fmaxf(o0.w + bias.w, 0.f);
        o1.x = fmaxf(o1.x + bias.x, 0.f); o1.y = fmaxf(o1.y + bias.y, 0.f);
        o1.z = fmaxf(o1.z + bias.z, 0.f); o1.w = fmaxf(o1.w + bias.w, 0.f);
        *(float4*)&go1[(size_t)(b * CL + i0 + rg * 2 + 0) * CATT + c] = o0;
        *(float4*)&go1[(size_t)(b * CL + i0 + rg * 2 + 1) * CATT + c] = o1;
    }
    __syncthreads();

    float* s_go = s_adj;
    if (t < 200) {
        *(float4*)&s_go[(rg * 2 + 0) * 104 + c] = o0;
        *(float4*)&s_go[(rg * 2 + 1) * 104 + c] = o1;
    }
    __syncthreads();

    if (t < 128) {
        int r = t >> 3, seg = t & 7;
        int e0 = seg * 13, e1 = e0 + 13 < 100 ? e0 + 13 : 100;
        float a = 0.f, c2 = 0.f;
        for (int e = e0; e < e1; ++e) {
            float v = s_go[r * 104 + e];
            a = fmaf(v, s_w1[e], a);
            c2 = fmaf(v, s_w2[e], c2);
        }
        a += __shfl_xor(a, 1); a += __shfl_xor(a, 2); a += __shfl_xor(a, 4);
        c2 += __shfl_xor(c2, 1); c2 += __shfl_xor(c2, 2); c2 += __shfl_xor(c2, 4);
        if (seg == 0) {
            s_g1row[r] = a;
            gW2S[b * CL + i0 + r] = c2;
        }
    }
    __syncthreads();

    if (t < 100) {
        float a = 0.f, s2 = 0.f;
#pragma unroll
        for (int r = 0; r < 16; ++r) {
            float v = s_go[r * 104 + t];
            a = fmaf(s_g1row[r], v, a);
            s2 += v;
        }
        atomicAdd(&t1[b * CATT + t], a);
        atomicAdd(&t2[b * CATT + t], s2);
    }
}

// ---------------------------------------------------------------------------
__global__ __launch_bounds__(256) void k7_gcn1(
    const float* __restrict__ adjW, const float* __restrict__ go1,
    const float* __restrict__ W_w, const float* __restrict__ W_b,
    const float* __restrict__ t1, const float* __restrict__ t2,
    const float* __restrict__ gW2S, const float* __restrict__ Wx_b,
    const float* __restrict__ amask, float* __restrict__ out1_raw)
{
    __shared__ float s_adj[16 * 260];
    __shared__ float s_b[100 * 104];
    __shared__ float s_ax[16 * 108];
    const int b = blockIdx.x >> 4, ic = blockIdx.x & 15;
    const int i0 = ic * 16;
    const int t = threadIdx.x;

    {
        const float4* asrc = (const float4*)adjW + (size_t)(b * CL + i0) * 64;
        for (int i = t; i < 1024; i += 256) {
            int row = i >> 6, c4 = i & 63;
            *(float4*)&s_adj[row * 260 + c4 * 4] = asrc[i];
        }
    }
    __syncthreads();

    const int cg = t % 25, rg = t / 25;
    const int c = cg * 4;
    float4 acc0 = make_float4(0.f, 0.f, 0.f, 0.f);
    float4 acc1 = make_float4(0.f, 0.f, 0.f, 0.f);
    for (int jt = 0; jt < 4; ++jt) {
        const float4* src = (const float4*)go1 + (size_t)(b * CL + jt * 64) * 25;
        for (int i = t; i < 1600; i += 256) {
            int row = i / 25, c4 = i % 25;
            *(float4*)&s_b[row * 104 + c4 * 4] = src[i];
        }
        __syncthreads();
        if (t < 200) {
#pragma unroll 2
            for (int kk = 0; kk < 64; kk += 4) {
                float4 a0 = *(const float4*)&s_adj[(rg * 2 + 0) * 260 + jt * 64 + kk];
                float4 a1 = *(const float4*)&s_adj[(rg * 2 + 1) * 260 + jt * 64 + kk];
                float4 w0 = *(const float4*)&s_b[(kk + 0) * 104 + c];
                float4 w1 = *(const float4*)&s_b[(kk + 1) * 104 + c];
                float4 w2 = *(const float4*)&s_b[(kk + 2) * 104 + c];
                float4 w3 = *(const float4*)&s_b[(kk + 3) * 104 + c];
                fma4(acc0, a0.x, w0); fma4(acc0, a0.y, w1); fma4(acc0, a0.z, w2); fma4(acc0, a0.w, w3);
                fma4(acc1, a1.x, w0); fma4(acc1, a1.y, w1); fma4(acc1, a1.z, w2); fma4(acc1, a1.w, w3);
            }
        }
        __syncthreads();
    }
    if (t < 200) {
        float wxbs = Wx_b[0] + Wx_b[1] + Wx_b[2] + Wx_b[3] + Wx_b[4];
        float4 t1v = *(const float4*)&t1[b * CATT + c];
        float4 t2v = *(const float4*)&t2[b * CATT + c];
        float gw0 = gW2S[b * CL + i0 + rg * 2 + 0] + wxbs;
        float gw1 = gW2S[b * CL + i0 + rg * 2 + 1] + wxbs;
        float4 r;
        r.x = (acc0.x + t1v.x + gw0 * t2v.x) * 0.2f;
        r.y = (acc0.y + t1v.y + gw0 * t2v.y) * 0.2f;
        r.z = (acc0.z + t1v.z + gw0 * t2v.z) * 0.2f;
        r.w = (acc0.w + t1v.w + gw0 * t2v.w) * 0.2f;
        *(float4*)&s_ax[(rg * 2 + 0) * 108 + c] = r;
        r.x = (acc1.x + t1v.x + gw1 * t2v.x) * 0.2f;
        r.y = (acc1.y + t1v.y + gw1 * t2v.y) * 0.2f;
        r.z = (acc1.z + t1v.z + gw1 * t2v.z) * 0.2f;
        r.w = (acc1.w + t1v.w + gw1 * t2v.w) * 0.2f;
        *(float4*)&s_ax[(rg * 2 + 1) * 108 + c] = r;
    }
    {
        const float4* ws4 = (const float4*)W_w;
        for (int i = t; i < 2500; i += 256) {
            int row = i / 25, c4 = i % 25;
            *(float4*)&s_b[row * 104 + c4 * 4] = ws4[i];
        }
    }
    __syncthreads();

    if (t < 200) {
        float4 o0 = make_float4(0.f, 0.f, 0.f, 0.f);
        float4 o1 = make_float4(0.f, 0.f, 0.f, 0.f);
#pragma unroll 2
        for (int k = 0; k < 100; k += 4) {
            float4 a0 = *(const float4*)&s_ax[(rg * 2 + 0) * 108 + k];
            float4 a1 = *(const float4*)&s_ax[(rg * 2 + 1) * 108 + k];
            float4 w0 = *(const float4*)&s_b[(k + 0) * 104 + c];
            float4 w1 = *(const float4*)&s_b[(k + 1) * 104 + c];
            float4 w2 = *(const float4*)&s_b[(k + 2) * 104 + c];
            float4 w3 = *(const float4*)&s_b[(k + 3) * 104 + c];
            fma4(o0, a0.x, w0); fma4(o0, a0.y, w1); fma4(o0, a0.z, w2); fma4(o0, a0.w, w3);
            fma4(o1, a1.x, w0); fma4(o1, a1.y, w1); fma4(o1, a1.z, w2); fma4(o1, a1.w, w3);
        }
        float4 bias = *(const float4*)&W_b[c];
        o0.x = fmaxf(o0.x + bias.x, 0.f); o0.y = fmaxf(o0.y + bias.y, 0.f);
        o0.z = fmaxf(o0.z + bias.z, 0.f); o0.w = fmaxf(o0.w + bias.w, 0.f);
        o1.x = fmaxf(o1.x + bias.x, 0.f); o1.y = fmaxf(o1.y + bias.y, 0.f);
        o1.z = fmaxf(o1.z + bias.z, 0.f); o1.w = fmaxf(o1.w + bias.w, 0.f);
        float4 ov[2] = { o0, o1 };
#pragma unroll
        for (int q = 0; q < 2; ++q) {
            int row = b * CL + i0 + rg * 2 + q;
            float m = amask[row];
            if (m != 0.f) {
                atomicAdd(&out1_raw[b * CATT + c + 0], m * ov[q].x);
                atomicAdd(&out1_raw[b * CATT + c + 1], m * ov[q].y);
                atomicAdd(&out1_raw[b * CATT + c + 2], m * ov[q].z);
                atomicAdd(&out1_raw[b * CATT + c + 3], m * ov[q].w);
            }
        }
    }
}

// ---------------------------------------------------------------------------
__global__ __launch_bounds__(64) void k8_small(
    const float* __restrict__ out1_raw, const float* __restrict__ aspwn,
    const float* __restrict__ clf_w, const float* __restrict__ clf_b,
    float* __restrict__ out)
{
    const int b = blockIdx.x, t = threadIdx.x;
    if (t < 3) {
        float rwn = 1.f / aspwn[b];
        float a = clf_b[t];
        for (int d = 0; d < CATT; ++d)
            a = fmaf(out1_raw[b * CATT + d] * rwn, clf_w[d * 3 + t], a);
        out[b * 3 + t] = a;
    }
}

// ---------------------------------------------------------------------------
extern "C" void kernel_launch(void* const* d_in, const int* in_sizes, int n_in,
                              void* d_out, int out_size, void* d_ws, size_t ws_size,
                              hipStream_t stream) {
    const float* seq     = (const float*)d_in[0];
    const int*   srcm    = (const int*)d_in[1];
    const float* amask   = (const float*)d_in[2];
    const float* shortm  = (const float*)d_in[3];
    const float* ln_a    = (const float*)d_in[4];
    const float* ln_b    = (const float*)d_in[5];
    const float* Wxx_w   = (const float*)d_in[6];
    const float* Wxx_b   = (const float*)d_in[7];
    const float* q_w     = (const float*)d_in[8];
    const float* q_b     = (const float*)d_in[9];
    const float* k_w     = (const float*)d_in[10];
    const float* k_b     = (const float*)d_in[11];
    const float* dense_w = (const float*)d_in[12];
    const float* dense_b = (const float*)d_in[13];
    const float* bias_m  = (const float*)d_in[14];
    const float* W_w     = (const float*)d_in[15];
    const float* W_b     = (const float*)d_in[16];
    const float* Wx_w    = (const float*)d_in[17];
    const float* Wx_b    = (const float*)d_in[18];
    const float* clf_w   = (const float*)d_in[19];
    const float* clf_b   = (const float*)d_in[20];
    float* out = (float*)d_out;

    float* ws         = (float*)d_ws;
    float* g          = ws;
    float* qt         = g + 819200;
    float* ktb        = qt + 819200;
    float* go1        = ktb + 819200;
    float* adjW       = go1 + 819200;
    float* aspect_raw = adjW + 2097152;
    float* t1         = aspect_raw + 3200;
    float* t2         = t1 + 3200;
    float* out1_raw   = t2 + 3200;
    float* gW2S       = out1_raw + 3200;   // 8192
    float* asp        = gW2S + 8192;       // 640
    float* aspwn      = asp + 640;         // 32

    hipMemsetAsync(aspect_raw, 0, 4 * 3200 * sizeof(float), stream);
    hipLaunchKernelGGL(k1_fused, dim3(512), dim3(256), 0, stream, seq, ln_a, ln_b,
                       Wxx_w, Wxx_b, q_w, q_b, k_w, k_b, amask, g, qt, ktb, aspect_raw);
    hipLaunchKernelGGL(k2_small, dim3(32), dim3(256), 0, stream,
                       aspect_raw, amask, dense_w, dense_b, asp, aspwn);
    hipLaunchKernelGGL(k45_attn_gcn0, dim3(512), dim3(256), 0, stream,
                       qt, ktb, asp, bias_m, srcm, shortm, Wx_w, g, W_w, W_b,
                       adjW, go1, t1, t2, gW2S);
    hipLaunchKernelGGL(k7_gcn1, dim3(512), dim3(256), 0, stream,
                       adjW, go1, W_w, W_b, t1, t2, gW2S, Wx_b, amask, out1_raw);
    hipLaunchKernelGGL(k8_small, dim3(32), dim3(64), 0, stream,
                       out1_raw, aspwn, clf_w, clf_b, out);
}